// Round 5
// baseline (324.021 us; speedup 1.0000x reference)
//
#include <hip/hip_runtime.h>
#include <hip/hip_bf16.h>

// Problem constants (fixed by the reference)
#define NROWS   200000
#define DSP     64      // spatial width
#define DST     131     // structural width
#define DSTP    136     // structural padded to 136 bf16 cols (272B rows, 16B-aligned)
#define DOUT    256
#define BM      64      // rows per block
#define NBLK    (NROWS / BM)   // 3125 exactly

typedef short bf8   __attribute__((ext_vector_type(8)));   // 8 bf16 (4 VGPRs)
typedef float f32x4 __attribute__((ext_vector_type(4)));

// f32 -> bf16 (RNE) on raw bits (wprep only)
__device__ __forceinline__ unsigned short f2bf(float x) {
    unsigned u = __float_as_uint(x);
    unsigned r = (u + 0x7fffu + ((u >> 16) & 1u)) >> 16;
    return (unsigned short)r;
}
// hot path: HW bf16 convert
__device__ __forceinline__ unsigned short bf1(float x) {
    __hip_bfloat16 h = __float2bfloat16(x);
    return *reinterpret_cast<unsigned short*>(&h);
}
__device__ __forceinline__ unsigned packbf2(float a, float b) {
    return (unsigned)bf1(a) | ((unsigned)bf1(b) << 16);
}
// bf16 pair (packed in u32) -> two f32
__device__ __forceinline__ float blo(unsigned u) { return __uint_as_float(u << 16); }
__device__ __forceinline__ float bhi(unsigned u) { return __uint_as_float(u & 0xffff0000u); }

union bf8u { bf8 b; uint4 u; };

__device__ __forceinline__ bf8 mk8(float4 u, float4 v) {
    bf8u r;
    r.u.x = packbf2(u.x, u.y);
    r.u.y = packbf2(u.z, u.w);
    r.u.z = packbf2(v.x, v.y);
    r.u.w = packbf2(v.z, v.w);
    return r.b;
}

// agg = 0.25 * (s0 + s1 + s2 + s3), elementwise on 8 bf16, f32 arithmetic
__device__ __forceinline__ bf8 aggsum(bf8 s0, bf8 s1, bf8 s2, bf8 s3) {
    bf8u a{s0}, b{s1}, c{s2}, d{s3}, r;
    #pragma unroll
    for (int i = 0; i < 4; ++i) {
        unsigned ua = (&a.u.x)[i], ub = (&b.u.x)[i];
        unsigned uc = (&c.u.x)[i], ud = (&d.u.x)[i];
        float lo = (blo(ua) + blo(ub)) + (blo(uc) + blo(ud));
        float hi = (bhi(ua) + bhi(ub)) + (bhi(uc) + bhi(ud));
        (&r.u.x)[i] = packbf2(lo * 0.25f, hi * 0.25f);
    }
    return r.b;
}

// ---------------------------------------------------------------------------
// Pack weights into MFMA B-fragment order:
//   entry(ks, cb, lane, j) = W[n][k], n = cb*16 + (lane&15), k = ks*32 + (lane>>4)*8 + j
// ---------------------------------------------------------------------------
__global__ __launch_bounds__(256) void wprep(const float* __restrict__ Wc,
                                             const float* __restrict__ Wa,
                                             short* __restrict__ w1p,
                                             short* __restrict__ w2p) {
    int idx = blockIdx.x * 256 + threadIdx.x;
    if (idx < 57344) {
        int j  = idx & 7;
        int l  = (idx >> 3) & 63;
        int cb = (idx >> 9) & 15;
        int ks = idx >> 13;
        int k  = ks * 32 + (l >> 4) * 8 + j;
        int n  = cb * 16 + (l & 15);
        float v = (k < 195) ? Wc[n * 195 + k] : 0.0f;
        w1p[idx] = (short)f2bf(v);
    } else {
        int id2 = idx - 57344;
        if (id2 < 40960) {
            int j  = id2 & 7;
            int l  = (id2 >> 3) & 63;
            int cb = (id2 >> 9) & 15;
            int ks = id2 >> 13;
            int k  = ks * 32 + (l >> 4) * 8 + j;
            int n  = cb * 16 + (l & 15);
            float v = (k < 131) ? Wa[n * 131 + k] : 0.0f;
            w2p[id2] = (short)f2bf(v);
        }
    }
}

// ---------------------------------------------------------------------------
// cvt: structural f32 [NROWS][131] -> sbf bf16 [NROWS][136] (cols 131..135 = 0)
// One row per half-wave: lanes 0..31 of each half cover cols 0..127 (float4),
// sub==0 lane also writes cols 128..135 via an overlapping load at col 127.
// ---------------------------------------------------------------------------
__global__ __launch_bounds__(256) void cvt(const float* __restrict__ st,
                                           unsigned short* __restrict__ sbf) {
    int wid = (blockIdx.x * 256 + threadIdx.x) >> 6;
    int l   = threadIdx.x & 63;
    int h   = l >> 5, sub = l & 31;
    int nw  = (gridDim.x * 256) >> 6;
    for (int pr = wid; pr < NROWS / 2; pr += nw) {
        int row = pr * 2 + h;
        const float* src = st + (size_t)row * DST;
        unsigned short* dst = sbf + (size_t)row * DSTP;
        float4 v = *(const float4*)(src + 4 * sub);
        uint2 wv;
        wv.x = packbf2(v.x, v.y);
        wv.y = packbf2(v.z, v.w);
        *(uint2*)(dst + 4 * sub) = wv;
        if (sub == 0) {
            float4 tl = *(const float4*)(src + 127);   // cols 127..130 (4B-aligned ok)
            uint4 tw;
            tw.x = packbf2(tl.y, tl.z);
            tw.y = packbf2(tl.w, 0.0f);
            tw.z = 0u;
            tw.w = 0u;
            *(uint4*)(dst + 128) = tw;
        }
    }
}

// ---------------------------------------------------------------------------
// mesh_gemm: no LDS, no barriers. Block = 4 waves; wave w computes the full
// 64-row tile x cols [w*64, w*64+64). MFMA A-fragments are loaded directly
// from global memory (per-lane 16B, 16 rows x 64B segments per instruction).
//   out1 = [spatial | structural] @ Wc^T + b_comb   (K-blocks ks=0..6)
//   out2 = 0.25*(self + 3 gathered rows) @ Wa^T + b_agg  (ks=0..4)
// ---------------------------------------------------------------------------
__global__ __launch_bounds__(256, 3) void mesh_gemm(
        const float* __restrict__ spatial,
        const unsigned short* __restrict__ sbf,
        const int*   __restrict__ neigh,
        const short* __restrict__ w1p,
        const short* __restrict__ w2p,
        const float* __restrict__ b_comb,
        const float* __restrict__ b_agg,
        float* __restrict__ out1,
        float* __restrict__ out2) {
    const int t  = threadIdx.x;
    const int w  = t >> 6;
    const int l  = t & 63;
    const int lr = l & 15;   // A row within 16 / D col within 16
    const int lk = l >> 4;   // k-chunk / D row-group
    const int r0 = blockIdx.x * BM;

    // per-m self row pointers (row = r0 + m*16 + lr)
    const float*          sp[4];
    const unsigned short* ss[4];
    #pragma unroll
    for (int m = 0; m < 4; ++m) {
        int row = r0 + m * 16 + lr;
        sp[m] = spatial + (size_t)row * DSP;
        ss[m] = sbf + (size_t)row * DSTP;
    }

    // ---------------- out1 ----------------
    f32x4 acc[4][4];
    #pragma unroll
    for (int m = 0; m < 4; ++m)
        #pragma unroll
        for (int n = 0; n < 4; ++n)
            acc[m][n] = (f32x4){0.f, 0.f, 0.f, 0.f};

    #pragma unroll
    for (int ks = 0; ks < 7; ++ks) {
        bf8 a[4];
        if (ks < 2) {           // spatial f32 -> bf16 in-register
            #pragma unroll
            for (int m = 0; m < 4; ++m) {
                const float* p = sp[m] + ks * 32 + lk * 8;
                float4 u = *(const float4*)(p);
                float4 v = *(const float4*)(p + 4);
                a[m] = mk8(u, v);
            }
        } else if (ks < 6) {    // structural bf16 direct
            #pragma unroll
            for (int m = 0; m < 4; ++m)
                a[m] = *(const bf8*)(ss[m] + (ks - 2) * 32 + lk * 8);
        } else {                // ks=6: struct cols 128..135 (lk==0 only)
            #pragma unroll
            for (int m = 0; m < 4; ++m) {
                bf8 z = {};
                if (lk == 0) z = *(const bf8*)(ss[m] + 128);
                a[m] = z;
            }
        }
        #pragma unroll
        for (int n = 0; n < 4; ++n) {
            int cb = w * 4 + n;
            bf8 b = *(const bf8*)(w1p + (((ks * 16 + cb) * 64 + l) << 3));
            #pragma unroll
            for (int m = 0; m < 4; ++m)
                acc[m][n] = __builtin_amdgcn_mfma_f32_16x16x32_bf16(
                                a[m], b, acc[m][n], 0, 0, 0);
        }
    }
    #pragma unroll
    for (int n = 0; n < 4; ++n) {
        int col = w * 64 + n * 16 + lr;
        float bv = b_comb[col];
        #pragma unroll
        for (int m = 0; m < 4; ++m)
            #pragma unroll
            for (int r = 0; r < 4; ++r)
                out1[(size_t)(r0 + m * 16 + lk * 4 + r) * DOUT + col]
                    = acc[m][n][r] + bv;
    }

    // ---------------- out2 ----------------
    // neigh indices: lane l holds the 3 indices of row r0+l
    const int rb = (r0 + l) * 3;
    int nq0 = neigh[rb + 0];
    int nq1 = neigh[rb + 1];
    int nq2 = neigh[rb + 2];

    const unsigned short* np[4][3];
    #pragma unroll
    for (int m = 0; m < 4; ++m) {
        int src = m * 16 + lr;
        int i0 = __shfl(nq0, src);
        int i1 = __shfl(nq1, src);
        int i2 = __shfl(nq2, src);
        np[m][0] = sbf + (size_t)i0 * DSTP;
        np[m][1] = sbf + (size_t)i1 * DSTP;
        np[m][2] = sbf + (size_t)i2 * DSTP;
    }

    f32x4 acc2[4][4];
    #pragma unroll
    for (int m = 0; m < 4; ++m)
        #pragma unroll
        for (int n = 0; n < 4; ++n)
            acc2[m][n] = (f32x4){0.f, 0.f, 0.f, 0.f};

    #pragma unroll
    for (int ks = 0; ks < 5; ++ks) {
        bf8 a[4];
        if (ks < 4) {
            int off = ks * 32 + lk * 8;
            #pragma unroll
            for (int m = 0; m < 4; ++m) {
                bf8 s0 = *(const bf8*)(ss[m]    + off);
                bf8 s1 = *(const bf8*)(np[m][0] + off);
                bf8 s2 = *(const bf8*)(np[m][1] + off);
                bf8 s3 = *(const bf8*)(np[m][2] + off);
                a[m] = aggsum(s0, s1, s2, s3);
            }
        } else {                // ks=4: cols 128..135 (lk==0 only)
            #pragma unroll
            for (int m = 0; m < 4; ++m) {
                bf8 z = {};
                if (lk == 0) {
                    bf8 s0 = *(const bf8*)(ss[m]    + 128);
                    bf8 s1 = *(const bf8*)(np[m][0] + 128);
                    bf8 s2 = *(const bf8*)(np[m][1] + 128);
                    bf8 s3 = *(const bf8*)(np[m][2] + 128);
                    z = aggsum(s0, s1, s2, s3);
                }
                a[m] = z;
            }
        }
        #pragma unroll
        for (int n = 0; n < 4; ++n) {
            int cb = w * 4 + n;
            bf8 b = *(const bf8*)(w2p + (((ks * 16 + cb) * 64 + l) << 3));
            #pragma unroll
            for (int m = 0; m < 4; ++m)
                acc2[m][n] = __builtin_amdgcn_mfma_f32_16x16x32_bf16(
                                a[m], b, acc2[m][n], 0, 0, 0);
        }
    }
    #pragma unroll
    for (int n = 0; n < 4; ++n) {
        int col = w * 64 + n * 16 + lr;
        float bv = b_agg[col];
        #pragma unroll
        for (int m = 0; m < 4; ++m)
            #pragma unroll
            for (int r = 0; r < 4; ++r)
                out2[(size_t)(r0 + m * 16 + lk * 4 + r) * DOUT + col]
                    = acc2[m][n][r] + bv;
    }
}

// ---------------------------------------------------------------------------
extern "C" void kernel_launch(void* const* d_in, const int* in_sizes, int n_in,
                              void* d_out, int out_size, void* d_ws, size_t ws_size,
                              hipStream_t stream) {
    const float* spatial    = (const float*)d_in[0];
    const float* structural = (const float*)d_in[1];
    const int*   neighbour  = (const int*)  d_in[2];
    const float* W_agg      = (const float*)d_in[3];
    const float* b_agg      = (const float*)d_in[4];
    const float* W_comb     = (const float*)d_in[5];
    const float* b_comb     = (const float*)d_in[6];

    float* out1 = (float*)d_out;
    float* out2 = out1 + (size_t)NROWS * DOUT;

    short* w1p = (short*)d_ws;                       // 57344 shorts
    short* w2p = w1p + 57344;                        // 40960 shorts
    unsigned short* sbf = (unsigned short*)((char*)d_ws + 196608);  // [NROWS][136] bf16

    wprep<<<384, 256, 0, stream>>>(W_comb, W_agg, w1p, w2p);
    cvt<<<2048, 256, 0, stream>>>(structural, sbf);
    mesh_gemm<<<NBLK, 256, 0, stream>>>(spatial, sbf, neighbour,
                                        w1p, w2p, b_comb, b_agg, out1, out2);
}

// Round 7
// 173.663 us; speedup vs baseline: 1.8658x; 1.8658x over previous
//
#include <hip/hip_runtime.h>
#include <hip/hip_bf16.h>

// Problem constants (fixed by the reference)
#define NROWS   200000
#define DSP     64      // spatial width
#define DST     131     // structural width
#define DOUT    256
#define K1PAD   224     // 195 padded to 7*32
#define K2PAD   160     // 131 padded to 5*32
#define NK1     7
#define NK2     5
#define BM      64      // rows per block
#define NBLK    (NROWS / BM)   // 3125 exactly
#define LD1     (K1PAD + 8)    // 232 shorts = 464 B row stride
#define LD2     (K2PAD + 8)    // 168 shorts = 336 B row stride

typedef short bf8   __attribute__((ext_vector_type(8)));   // 8 bf16 (4 VGPRs)
typedef float f32x4 __attribute__((ext_vector_type(4)));
typedef float f4v   __attribute__((ext_vector_type(4)));   // for nontemporal builtins

// f32 -> bf16 (RNE) on raw bits (cold path / wprep only)
__device__ __forceinline__ unsigned short f2bf(float x) {
    unsigned u = __float_as_uint(x);
    unsigned r = (u + 0x7fffu + ((u >> 16) & 1u)) >> 16;
    return (unsigned short)r;
}

// hot path: HW bf16 convert
__device__ __forceinline__ unsigned short bf1(float x) {
    __hip_bfloat16 h = __float2bfloat16(x);
    return *reinterpret_cast<unsigned short*>(&h);
}
__device__ __forceinline__ unsigned packbf2(float a, float b) {
    return (unsigned)bf1(a) | ((unsigned)bf1(b) << 16);
}

// ---------------------------------------------------------------------------
// Pack weights into MFMA B-fragment order:
//   entry(ks, cb, lane, j) = W[n][k], n = cb*16 + (lane&15), k = ks*32 + (lane>>4)*8 + j
// ---------------------------------------------------------------------------
__global__ __launch_bounds__(256) void wprep(const float* __restrict__ Wc,
                                             const float* __restrict__ Wa,
                                             short* __restrict__ w1p,
                                             short* __restrict__ w2p) {
    int idx = blockIdx.x * 256 + threadIdx.x;
    if (idx < 57344) {
        int j  = idx & 7;
        int l  = (idx >> 3) & 63;
        int cb = (idx >> 9) & 15;
        int ks = idx >> 13;
        int k  = ks * 32 + (l >> 4) * 8 + j;
        int n  = cb * 16 + (l & 15);
        float v = (k < 195) ? Wc[n * 195 + k] : 0.0f;
        w1p[idx] = (short)f2bf(v);
    } else {
        int id2 = idx - 57344;
        if (id2 < 40960) {
            int j  = id2 & 7;
            int l  = (id2 >> 3) & 63;
            int cb = (id2 >> 9) & 15;
            int ks = id2 >> 13;
            int k  = ks * 32 + (l >> 4) * 8 + j;
            int n  = cb * 16 + (l & 15);
            float v = (k < 131) ? Wa[n * 131 + k] : 0.0f;
            w2p[id2] = (short)f2bf(v);
        }
    }
}

// ---------------------------------------------------------------------------
// MFMA core: LDS A-tile [BM][LDPAD] (bf16), fragment-packed B in wp,
// computes the BMx256 tile and stores f32 + bias via NON-TEMPORAL stores
// (no-allocate: keep the streaming output from evicting the gather working
// set (structural) out of L2/L3).
// ---------------------------------------------------------------------------
template <int NK, int LDPAD, int MREP>
__device__ __forceinline__ void mfma_tile_and_store(
        const short (*lds)[LDPAD],
        const short* __restrict__ wp,
        const float* __restrict__ bias,
        float* __restrict__ out,
        int r0, int t) {
    const int wave = t >> 6;
    const int l    = t & 63;
    const int lr   = l & 15;   // A-row / D-col
    const int lk   = l >> 4;   // k-group / D-row-group

    f32x4 acc[MREP][4];
    #pragma unroll
    for (int m = 0; m < MREP; ++m)
        #pragma unroll
        for (int n = 0; n < 4; ++n)
            acc[m][n] = (f32x4){0.f, 0.f, 0.f, 0.f};

    #pragma unroll
    for (int ks = 0; ks < NK; ++ks) {
        bf8 a[MREP], bb[4];
        #pragma unroll
        for (int m = 0; m < MREP; ++m)
            a[m] = *(const bf8*)&lds[m * 16 + lr][ks * 32 + lk * 8];
        #pragma unroll
        for (int n = 0; n < 4; ++n) {
            int cb = wave * 4 + n;
            bb[n] = *(const bf8*)(wp + (((ks * 16 + cb) * 64 + l) << 3));
        }
        #pragma unroll
        for (int m = 0; m < MREP; ++m)
            #pragma unroll
            for (int n = 0; n < 4; ++n)
                acc[m][n] = __builtin_amdgcn_mfma_f32_16x16x32_bf16(
                                a[m], bb[n], acc[m][n], 0, 0, 0);
    }

    #pragma unroll
    for (int n = 0; n < 4; ++n) {
        int col = wave * 64 + n * 16 + lr;
        float bv = bias[col];
        #pragma unroll
        for (int m = 0; m < MREP; ++m) {
            #pragma unroll
            for (int r = 0; r < 4; ++r) {
                int row = m * 16 + lk * 4 + r;
                __builtin_nontemporal_store(
                    acc[m][n][r] + bv,
                    &out[(size_t)(r0 + row) * DOUT + col]);
            }
        }
    }
}

// ---------------------------------------------------------------------------
// Fused kernel, BM=64 (identical structure to R4; only cache hints changed):
//  - spatial loads: non-temporal (single-use stream, don't pollute L2/L3)
//  - structural loads (self + gather): NORMAL (they are the L3 working set)
//  - output stores: non-temporal (in mfma_tile_and_store)
// ---------------------------------------------------------------------------
__global__ __launch_bounds__(256, 3) void fused(
        const float* __restrict__ spatial,
        const float* __restrict__ structural,
        const int*   __restrict__ neigh,
        const short* __restrict__ w1p,
        const short* __restrict__ w2p,
        const float* __restrict__ b_comb,
        const float* __restrict__ b_agg,
        float* __restrict__ out1,
        float* __restrict__ out2) {
    __shared__ short lds1[BM][LD1];
    __shared__ short lds2[BM][LD2];
    const int t  = threadIdx.x;
    const int w  = t >> 6;
    const int l  = t & 63;
    const int r0 = blockIdx.x * BM;

    // ---- per-wave neigh preload: lanes 0..47 hold 16 rows x 3 indices ----
    int nv = 0;
    if (l < 48) {
        int lrow = l / 3;                 // 0..15 (local row)
        int lq   = l - lrow * 3;          // 0..2
        nv = neigh[(r0 + w * 16 + lrow) * 3 + lq];
    }

    // ---- zero pads (per-wave rows; DS program order protects overwrites) ----
    {
        int row = w * 16 + (l >> 2);
        int k   = l & 3;
        *(uint4*)&lds1[row][192 + 8 * k] = make_uint4(0, 0, 0, 0);  // cols 192..223
        *(uint4*)&lds2[row][128 + 8 * k] = make_uint4(0, 0, 0, 0);  // cols 128..159
    }

    // ---- stage spatial -> lds1 cols 0..63 (non-temporal float4 loads) ----
    {
        int h  = t & 15;
        int sl = t >> 4;
        #pragma unroll
        for (int p = 0; p < 4; ++p) {
            int row = sl + 16 * p;
            f4v v = __builtin_nontemporal_load(
                (const f4v*)(spatial + (size_t)(r0 + row) * DSP + 4 * h));
            uint2 wv;
            wv.x = packbf2(v.x, v.y);
            wv.y = packbf2(v.z, v.w);
            *(uint2*)&lds1[row][4 * h] = wv;
        }
    }

    // ---- gather staging (normal/cacheable loads) ----
    {
        const char* sbase = (const char*)structural;
        const int h   = l >> 5;           // row half
        const int sub = l & 31;           // 16B chunk index (cols 4*sub..4*sub+3)
        #pragma unroll
        for (int p = 0; p < 8; ++p) {
            int local = 2 * p + h;        // 0..15
            int row   = w * 16 + local;
            int srow  = r0 + row;
            int n0 = __shfl(nv, 3 * local + 0);
            int n1 = __shfl(nv, 3 * local + 1);
            int n2 = __shfl(nv, 3 * local + 2);

            unsigned co = 16u * (unsigned)sub;
            float4 v0 = *(const float4*)(sbase + (unsigned)srow * 524u + co);
            float4 v1 = *(const float4*)(sbase + (unsigned)n0   * 524u + co);
            float4 v2 = *(const float4*)(sbase + (unsigned)n1   * 524u + co);
            float4 v3 = *(const float4*)(sbase + (unsigned)n2   * 524u + co);

            // lds1 self: cols 64+4*sub .. 64+4*sub+3
            uint2 wa;
            wa.x = packbf2(v0.x, v0.y);
            wa.y = packbf2(v0.z, v0.w);
            *(uint2*)&lds1[row][64 + 4 * sub] = wa;

            // lds2 agg
            float sx = (v0.x + v1.x + v2.x + v3.x) * 0.25f;
            float sy = (v0.y + v1.y + v2.y + v3.y) * 0.25f;
            float sz = (v0.z + v1.z + v2.z + v3.z) * 0.25f;
            float sw = (v0.w + v1.w + v2.w + v3.w) * 0.25f;
            uint2 wb;
            wb.x = packbf2(sx, sy);
            wb.y = packbf2(sz, sw);
            *(uint2*)&lds2[row][4 * sub] = wb;

            if (sub == 31) {
                // tail: structural cols 128..130 (overlapping load at col 127)
                unsigned to = 508u;   // byte offset of col 127
                float4 t0 = *(const float4*)(sbase + (unsigned)srow * 524u + to);
                float4 t1 = *(const float4*)(sbase + (unsigned)n0   * 524u + to);
                float4 t2 = *(const float4*)(sbase + (unsigned)n1   * 524u + to);
                float4 t3 = *(const float4*)(sbase + (unsigned)n2   * 524u + to);
                // lds1: cols 192..194  (y,z,w = cols 128,129,130)
                *(unsigned*)&lds1[row][192] = packbf2(t0.y, t0.z);
                lds1[row][194] = (short)bf1(t0.w);
                float ty = (t0.y + t1.y + t2.y + t3.y) * 0.25f;
                float tz = (t0.z + t1.z + t2.z + t3.z) * 0.25f;
                float tw = (t0.w + t1.w + t2.w + t3.w) * 0.25f;
                *(unsigned*)&lds2[row][128] = packbf2(ty, tz);
                lds2[row][130] = (short)bf1(tw);
            }
        }
    }
    __syncthreads();

    mfma_tile_and_store<NK1, LD1, BM / 16>(lds1, w1p, b_comb, out1, r0, t);
    mfma_tile_and_store<NK2, LD2, BM / 16>(lds2, w2p, b_agg, out2, r0, t);
}

// ---------------------------------------------------------------------------
extern "C" void kernel_launch(void* const* d_in, const int* in_sizes, int n_in,
                              void* d_out, int out_size, void* d_ws, size_t ws_size,
                              hipStream_t stream) {
    const float* spatial    = (const float*)d_in[0];
    const float* structural = (const float*)d_in[1];
    const int*   neighbour  = (const int*)  d_in[2];
    const float* W_agg      = (const float*)d_in[3];
    const float* b_agg      = (const float*)d_in[4];
    const float* W_comb     = (const float*)d_in[5];
    const float* b_comb     = (const float*)d_in[6];

    float* out1 = (float*)d_out;
    float* out2 = out1 + (size_t)NROWS * DOUT;

    short* w1p = (short*)d_ws;          // 57344 shorts
    short* w2p = w1p + 57344;           // 40960 shorts

    wprep<<<384, 256, 0, stream>>>(W_comb, W_agg, w1p, w2p);
    fused<<<NBLK, 256, 0, stream>>>(spatial, structural, neighbour,
                                    w1p, w2p, b_comb, b_agg, out1, out2);
}

// Round 8
// 171.835 us; speedup vs baseline: 1.8857x; 1.0106x over previous
//
#include <hip/hip_runtime.h>
#include <hip/hip_bf16.h>

// Problem constants (fixed by the reference)
#define NROWS   200000
#define DSP     64      // spatial width
#define DST     131     // structural width
#define DOUT    256
#define K1PAD   224     // 195 padded to 7*32
#define K2PAD   160     // 131 padded to 5*32
#define NK1     7
#define NK2     5
#define BM      64      // rows per block
#define NBLK    (NROWS / BM)   // 3125 exactly
#define LD1     (K1PAD + 8)    // 232 shorts = 464 B row stride
#define LD2     (K2PAD + 8)    // 168 shorts = 336 B row stride

typedef short bf8   __attribute__((ext_vector_type(8)));   // 8 bf16 (4 VGPRs)
typedef float f32x4 __attribute__((ext_vector_type(4)));
typedef float f4v   __attribute__((ext_vector_type(4)));   // for nontemporal builtins

// f32 -> bf16 (RNE) on raw bits (cold path / wprep only)
__device__ __forceinline__ unsigned short f2bf(float x) {
    unsigned u = __float_as_uint(x);
    unsigned r = (u + 0x7fffu + ((u >> 16) & 1u)) >> 16;
    return (unsigned short)r;
}

// hot path: HW bf16 convert
__device__ __forceinline__ unsigned short bf1(float x) {
    __hip_bfloat16 h = __float2bfloat16(x);
    return *reinterpret_cast<unsigned short*>(&h);
}
__device__ __forceinline__ unsigned packbf2(float a, float b) {
    return (unsigned)bf1(a) | ((unsigned)bf1(b) << 16);
}

// ---------------------------------------------------------------------------
// Pack weights into MFMA B-fragment order:
//   entry(ks, cb, lane, j) = W[n][k], n = cb*16 + (lane&15), k = ks*32 + (lane>>4)*8 + j
// ---------------------------------------------------------------------------
__global__ __launch_bounds__(256) void wprep(const float* __restrict__ Wc,
                                             const float* __restrict__ Wa,
                                             short* __restrict__ w1p,
                                             short* __restrict__ w2p) {
    int idx = blockIdx.x * 256 + threadIdx.x;
    if (idx < 57344) {
        int j  = idx & 7;
        int l  = (idx >> 3) & 63;
        int cb = (idx >> 9) & 15;
        int ks = idx >> 13;
        int k  = ks * 32 + (l >> 4) * 8 + j;
        int n  = cb * 16 + (l & 15);
        float v = (k < 195) ? Wc[n * 195 + k] : 0.0f;
        w1p[idx] = (short)f2bf(v);
    } else {
        int id2 = idx - 57344;
        if (id2 < 40960) {
            int j  = id2 & 7;
            int l  = (id2 >> 3) & 63;
            int cb = (id2 >> 9) & 15;
            int ks = id2 >> 13;
            int k  = ks * 32 + (l >> 4) * 8 + j;
            int n  = cb * 16 + (l & 15);
            float v = (k < 131) ? Wa[n * 131 + k] : 0.0f;
            w2p[id2] = (short)f2bf(v);
        }
    }
}

// ---------------------------------------------------------------------------
// MFMA core: LDS A-tile [BM][LDPAD] (bf16), fragment-packed B in wp,
// computes the BMx256 tile and stores f32 + bias via NON-TEMPORAL stores
// (no-allocate: keeps the streaming output from evicting the gather working
// set (structural) out of L2/L3 — confirmed -63us in R7).
// ---------------------------------------------------------------------------
template <int NK, int LDPAD, int MREP>
__device__ __forceinline__ void mfma_tile_and_store(
        const short (*lds)[LDPAD],
        const short* __restrict__ wp,
        const float* __restrict__ bias,
        float* __restrict__ out,
        int r0, int t) {
    const int wave = t >> 6;
    const int l    = t & 63;
    const int lr   = l & 15;   // A-row / D-col
    const int lk   = l >> 4;   // k-group / D-row-group

    f32x4 acc[MREP][4];
    #pragma unroll
    for (int m = 0; m < MREP; ++m)
        #pragma unroll
        for (int n = 0; n < 4; ++n)
            acc[m][n] = (f32x4){0.f, 0.f, 0.f, 0.f};

    #pragma unroll
    for (int ks = 0; ks < NK; ++ks) {
        bf8 a[MREP], bb[4];
        #pragma unroll
        for (int m = 0; m < MREP; ++m)
            a[m] = *(const bf8*)&lds[m * 16 + lr][ks * 32 + lk * 8];
        #pragma unroll
        for (int n = 0; n < 4; ++n) {
            int cb = wave * 4 + n;
            bb[n] = *(const bf8*)(wp + (((ks * 16 + cb) * 64 + l) << 3));
        }
        #pragma unroll
        for (int m = 0; m < MREP; ++m)
            #pragma unroll
            for (int n = 0; n < 4; ++n)
                acc[m][n] = __builtin_amdgcn_mfma_f32_16x16x32_bf16(
                                a[m], bb[n], acc[m][n], 0, 0, 0);
    }

    #pragma unroll
    for (int n = 0; n < 4; ++n) {
        int col = wave * 64 + n * 16 + lr;
        float bv = bias[col];
        #pragma unroll
        for (int m = 0; m < MREP; ++m) {
            #pragma unroll
            for (int r = 0; r < 4; ++r) {
                int row = m * 16 + lk * 4 + r;
                __builtin_nontemporal_store(
                    acc[m][n][r] + bv,
                    &out[(size_t)(r0 + row) * DOUT + col]);
            }
        }
    }
}

// ---------------------------------------------------------------------------
// Fused kernel, BM=64. R7 structure + deeper gather pipeline:
//  - 2 rows (8 float4 gathers) in flight per loop iteration
//  - 3-col tail hoisted into one 48-lane pass (4 scalar loads total)
//  - NT: spatial loads, neigh loads, output stores
// ---------------------------------------------------------------------------
__global__ __launch_bounds__(256, 3) void fused(
        const float* __restrict__ spatial,
        const float* __restrict__ structural,
        const int*   __restrict__ neigh,
        const short* __restrict__ w1p,
        const short* __restrict__ w2p,
        const float* __restrict__ b_comb,
        const float* __restrict__ b_agg,
        float* __restrict__ out1,
        float* __restrict__ out2) {
    __shared__ short lds1[BM][LD1];
    __shared__ short lds2[BM][LD2];
    const int t  = threadIdx.x;
    const int w  = t >> 6;
    const int l  = t & 63;
    const int r0 = blockIdx.x * BM;

    // ---- per-wave neigh preload: lanes 0..47 hold 16 rows x 3 indices ----
    int nv = 0;
    if (l < 48) {
        int lrow = l / 3;                 // 0..15 (local row)
        int lq   = l - lrow * 3;          // 0..2
        nv = __builtin_nontemporal_load(
                 neigh + (r0 + w * 16 + lrow) * 3 + lq);
    }

    // ---- zero pads (per-wave rows; same-wave DS program order protects
    //      the later tail writes to cols 192..194 / 128..130) ----
    {
        int row = w * 16 + (l >> 2);
        int k   = l & 3;
        *(uint4*)&lds1[row][192 + 8 * k] = make_uint4(0, 0, 0, 0);  // cols 192..223
        *(uint4*)&lds2[row][128 + 8 * k] = make_uint4(0, 0, 0, 0);  // cols 128..159
    }

    // ---- stage spatial -> lds1 cols 0..63 (non-temporal float4 loads) ----
    {
        int h  = t & 15;
        int sl = t >> 4;
        #pragma unroll
        for (int p = 0; p < 4; ++p) {
            int row = sl + 16 * p;
            f4v v = __builtin_nontemporal_load(
                (const f4v*)(spatial + (size_t)(r0 + row) * DSP + 4 * h));
            uint2 wv;
            wv.x = packbf2(v.x, v.y);
            wv.y = packbf2(v.z, v.w);
            *(uint2*)&lds1[row][4 * h] = wv;
        }
    }

    // ---- gather staging: 2 rows in flight per iteration ----
    {
        const char* sbase = (const char*)structural;
        const int h   = l >> 5;           // row half
        const int sub = l & 31;           // 16B chunk index (cols 4*sub..4*sub+3)
        const unsigned co = 16u * (unsigned)sub;
        #pragma unroll
        for (int pp = 0; pp < 4; ++pp) {
            int localA = 4 * pp + h;      // pass 2pp
            int localB = 4 * pp + 2 + h;  // pass 2pp+1
            int rowA = w * 16 + localA;
            int rowB = w * 16 + localB;
            int srowA = r0 + rowA;
            int srowB = r0 + rowB;
            int a0 = __shfl(nv, 3 * localA + 0);
            int a1 = __shfl(nv, 3 * localA + 1);
            int a2 = __shfl(nv, 3 * localA + 2);
            int b0 = __shfl(nv, 3 * localB + 0);
            int b1 = __shfl(nv, 3 * localB + 1);
            int b2 = __shfl(nv, 3 * localB + 2);

            // issue all 8 loads before consuming any
            float4 va0 = *(const float4*)(sbase + (unsigned)srowA * 524u + co);
            float4 va1 = *(const float4*)(sbase + (unsigned)a0    * 524u + co);
            float4 va2 = *(const float4*)(sbase + (unsigned)a1    * 524u + co);
            float4 va3 = *(const float4*)(sbase + (unsigned)a2    * 524u + co);
            float4 vb0 = *(const float4*)(sbase + (unsigned)srowB * 524u + co);
            float4 vb1 = *(const float4*)(sbase + (unsigned)b0    * 524u + co);
            float4 vb2 = *(const float4*)(sbase + (unsigned)b1    * 524u + co);
            float4 vb3 = *(const float4*)(sbase + (unsigned)b2    * 524u + co);

            // row A
            {
                uint2 wa;
                wa.x = packbf2(va0.x, va0.y);
                wa.y = packbf2(va0.z, va0.w);
                *(uint2*)&lds1[rowA][64 + 4 * sub] = wa;
                float sx = (va0.x + va1.x + va2.x + va3.x) * 0.25f;
                float sy = (va0.y + va1.y + va2.y + va3.y) * 0.25f;
                float sz = (va0.z + va1.z + va2.z + va3.z) * 0.25f;
                float sw = (va0.w + va1.w + va2.w + va3.w) * 0.25f;
                uint2 wb;
                wb.x = packbf2(sx, sy);
                wb.y = packbf2(sz, sw);
                *(uint2*)&lds2[rowA][4 * sub] = wb;
            }
            // row B
            {
                uint2 wa;
                wa.x = packbf2(vb0.x, vb0.y);
                wa.y = packbf2(vb0.z, vb0.w);
                *(uint2*)&lds1[rowB][64 + 4 * sub] = wa;
                float sx = (vb0.x + vb1.x + vb2.x + vb3.x) * 0.25f;
                float sy = (vb0.y + vb1.y + vb2.y + vb3.y) * 0.25f;
                float sz = (vb0.z + vb1.z + vb2.z + vb3.z) * 0.25f;
                float sw = (vb0.w + vb1.w + vb2.w + vb3.w) * 0.25f;
                uint2 wb;
                wb.x = packbf2(sx, sy);
                wb.y = packbf2(sz, sw);
                *(uint2*)&lds2[rowB][4 * sub] = wb;
            }
        }

        // ---- tail: cols 128..130 for all 16 rows in ONE 48-lane pass ----
        if (l < 48) {
            int lrow = l / 3;
            int q    = l - 3 * lrow;      // 0..2
            int row  = w * 16 + lrow;
            int srow = r0 + row;
            int i0 = __shfl(nv, 3 * lrow + 0);
            int i1 = __shfl(nv, 3 * lrow + 1);
            int i2 = __shfl(nv, 3 * lrow + 2);
            unsigned off = (unsigned)(128 + q) * 4u;
            float s0 = *(const float*)(sbase + (unsigned)srow * 524u + off);
            float s1 = *(const float*)(sbase + (unsigned)i0   * 524u + off);
            float s2 = *(const float*)(sbase + (unsigned)i1   * 524u + off);
            float s3 = *(const float*)(sbase + (unsigned)i2   * 524u + off);
            lds1[row][192 + q] = (short)bf1(s0);
            lds2[row][128 + q] = (short)bf1((s0 + s1 + s2 + s3) * 0.25f);
        }
    }
    __syncthreads();

    mfma_tile_and_store<NK1, LD1, BM / 16>(lds1, w1p, b_comb, out1, r0, t);
    mfma_tile_and_store<NK2, LD2, BM / 16>(lds2, w2p, b_agg, out2, r0, t);
}

// ---------------------------------------------------------------------------
extern "C" void kernel_launch(void* const* d_in, const int* in_sizes, int n_in,
                              void* d_out, int out_size, void* d_ws, size_t ws_size,
                              hipStream_t stream) {
    const float* spatial    = (const float*)d_in[0];
    const float* structural = (const float*)d_in[1];
    const int*   neighbour  = (const int*)  d_in[2];
    const float* W_agg      = (const float*)d_in[3];
    const float* b_agg      = (const float*)d_in[4];
    const float* W_comb     = (const float*)d_in[5];
    const float* b_comb     = (const float*)d_in[6];

    float* out1 = (float*)d_out;
    float* out2 = out1 + (size_t)NROWS * DOUT;

    short* w1p = (short*)d_ws;          // 57344 shorts
    short* w2p = w1p + 57344;           // 40960 shorts

    wprep<<<384, 256, 0, stream>>>(W_comb, W_agg, w1p, w2p);
    fused<<<NBLK, 256, 0, stream>>>(spatial, structural, neighbour,
                                    w1p, w2p, b_comb, b_agg, out1, out2);
}